// Round 7
// baseline (202.365 us; speedup 1.0000x reference)
//
#include <hip/hip_runtime.h>

#define NH   12
#define ND   64
#define NSEQ 4096
#define NIT  16
#define MM   256   // rows per iteration chunk

// LDS pitches (bf16 elements); all access patterns verified <=2-way bank alias
#define T_P  264   // XT/ET pitch
#define W_P  72    // WBT pitch

#define SM_XT   0
#define SM_ET   33792      // 64*264*2
#define SM_WBT  67584      // + 64*72*2 = 76800 used
#define SM_TOTAL 98304     // padded: 1 block/CU -> compiler budgets 128 VGPR (R6-proven)

typedef __bf16 bf16_t;
typedef bf16_t bf16x8 __attribute__((ext_vector_type(8)));
typedef float  f32x4  __attribute__((ext_vector_type(4)));

static __device__ __forceinline__ unsigned short f2bf(float f) {
    union { float f; unsigned u; } v; v.f = f;
    return (unsigned short)((v.u + 0x7FFFu + ((v.u >> 16) & 1u)) >> 16);
}

static __device__ __forceinline__ bf16x8 pack8(float4 a, float4 b) {
    union { unsigned short u[8]; bf16x8 v; } r;
    r.u[0] = f2bf(a.x); r.u[1] = f2bf(a.y); r.u[2] = f2bf(a.z); r.u[3] = f2bf(a.w);
    r.u[4] = f2bf(b.x); r.u[5] = f2bf(b.y); r.u[6] = f2bf(b.z); r.u[7] = f2bf(b.w);
    return r.v;
}

// Barrier draining ONLY LDS ops; global loads/stores stay in flight across it.
static __device__ __forceinline__ void barrier_lds() {
    asm volatile("s_waitcnt lgkmcnt(0)" ::: "memory");
    __builtin_amdgcn_s_barrier();
    asm volatile("" ::: "memory");
}

extern "C" __global__ void __launch_bounds__(1024)
ttt_fused(const float* __restrict__ qg, const float* __restrict__ kg,
          const float* __restrict__ vg, const float* __restrict__ Wi,
          float* __restrict__ outg)
{
    __shared__ char smem[SM_TOTAL] __attribute__((aligned(16)));
    unsigned short* XT  = (unsigned short*)(smem + SM_XT);   // x_tr transposed [d][m]
    unsigned short* ET  = (unsigned short*)(smem + SM_ET);   // err [e][m]
    unsigned short* WBT = (unsigned short*)(smem + SM_WBT);  // W transposed bf16 [e][d]

    const int tid  = threadIdx.x;
    const int lane = tid & 63;
    const int wv   = tid >> 6;      // wave 0..15
    const int g    = lane >> 4;     // 0..3
    const int ln   = lane & 15;     // 0..15

    const int bh = blockIdx.x;
    const int b  = bh / NH;
    const int h  = bh - b * NH;

    const float* kb = kg + (size_t)bh * NSEQ * ND;
    const float* vb = vg + (size_t)bh * NSEQ * ND;
    const float* qb = qg + (size_t)bh * NSEQ * ND;
    float* ob = outg + (size_t)b * NSEQ * (NH * ND) + h * ND;

    const int r0 = wv << 4;          // wave's 16-row m-slice (A and C)
    const int d0 = (wv >> 2) << 4;   // wave's grad tile (B)
    const int e0 = (wv & 3) << 4;
    const float scale = 1.0f / 16384.0f;  // LR / (m*D)

    // XT staging ownership: thread -> rows (sR, sR+1) x cols sC..sC+7
    const int sR = (tid & 127) << 1;   // 0..254, even
    const int sC = (tid >> 7) << 3;    // 0..56

    // ---- prologue: issue chunk-0 globals
    float4 ks[4], xq[4], qr[4];
    float  vq[4][4];   // vq[et][j] = y[r0+4g+j][16et+ln]  (D-fragment layout)
    {
        const float* kr = kb + (size_t)sR * ND + sC;
        ks[0] = *(const float4*)(kr);
        ks[1] = *(const float4*)(kr + 4);
        ks[2] = *(const float4*)(kr + ND);
        ks[3] = *(const float4*)(kr + ND + 4);
        const float* xr = kb + (size_t)(r0 + ln) * ND;
        xq[0] = *(const float4*)(xr + (g << 3));
        xq[1] = *(const float4*)(xr + (g << 3) + 4);
        xq[2] = *(const float4*)(xr + 32 + (g << 3));
        xq[3] = *(const float4*)(xr + 32 + (g << 3) + 4);
        const float* vp = vb + ((size_t)r0 + (g << 2)) * ND + ln;
        #pragma unroll
        for (int et = 0; et < 4; ++et)
            #pragma unroll
            for (int j = 0; j < 4; ++j)
                vq[et][j] = vp[(size_t)j * ND + (et << 4)];
    }

    // ---- W_init -> wf regs (wave-private f32 master) + WBT bf16
    float wf[4];
    {
        const float* wp = Wi + (size_t)h * ND * ND;
        ushort4 wq; unsigned short* wqp = (unsigned short*)&wq;
        #pragma unroll
        for (int j = 0; j < 4; ++j) {
            wf[j] = wp[(size_t)(d0 + (g << 2) + j) * ND + e0 + ln];
            wqp[j] = f2bf(wf[j]);
        }
        *(ushort4*)&WBT[(e0 + ln) * W_P + d0 + (g << 2)] = wq;
    }
    barrier_lds();   // WBT(W_0) visible

    for (int it = 0; it < NIT; ++it) {
        // ================= region 1: stage XT(it) | A(it) | C(it-1) =================
        // stage XT(it) from ks (consumed immediately; 2-way bank pattern)
        {
            #pragma unroll
            for (int j = 0; j < 8; ++j) {
                float flo = (j < 4) ? ((const float*)&ks[0])[j] : ((const float*)&ks[1])[j - 4];
                float fhi = (j < 4) ? ((const float*)&ks[2])[j] : ((const float*)&ks[3])[j - 4];
                *(unsigned*)&XT[(sC + j) * T_P + sR] =
                    (unsigned)f2bf(flo) | ((unsigned)f2bf(fhi) << 16);
            }
        }

        // issue ks(it+1) early: slack = A + C + alpha + B (>2K cycles)
        if (it + 1 < NIT) {
            const float* kr = kb + (size_t)((it + 1) * MM + sR) * ND + sC;
            ks[0] = *(const float4*)(kr);
            ks[1] = *(const float4*)(kr + 4);
            ks[2] = *(const float4*)(kr + ND);
            ks[3] = *(const float4*)(kr + ND + 4);
        }

        // A(it) + C(it-1) fused over e-tiles: one WBT fragment serves both
        {
            bf16x8 xa0 = pack8(xq[0], xq[1]);   // x[r0+ln][k 0..31 slice]
            bf16x8 xa1 = pack8(xq[2], xq[3]);   // x[r0+ln][k 32..63 slice]
            bf16x8 aq0, aq1;
            if (it > 0) { aq0 = pack8(qr[0], qr[1]); aq1 = pack8(qr[2], qr[3]); }

            #pragma unroll
            for (int et = 0; et < 4; ++et) {
                bf16x8 w0 = *(const bf16x8*)&WBT[((et << 4) + ln) * W_P + (g << 3)];
                bf16x8 w1 = *(const bf16x8*)&WBT[((et << 4) + ln) * W_P + 32 + (g << 3)];

                // err[m][e]: A = x-frag (regs), B = W-frag
                f32x4 ae = {0.f, 0.f, 0.f, 0.f};
                ae = __builtin_amdgcn_mfma_f32_16x16x32_bf16(xa0, w0, ae, 0, 0, 0);
                ae = __builtin_amdgcn_mfma_f32_16x16x32_bf16(xa1, w1, ae, 0, 0, 0);
                ushort4 ew; unsigned short* ewp = (unsigned short*)&ew;
                ewp[0] = f2bf(ae[0] - vq[et][0]);
                ewp[1] = f2bf(ae[1] - vq[et][1]);
                ewp[2] = f2bf(ae[2] - vq[et][2]);
                ewp[3] = f2bf(ae[3] - vq[et][3]);
                *(ushort4*)&ET[((et << 4) + ln) * T_P + r0 + (g << 2)] = ew;  // [e][m] direct

                // C(it-1): out = x_te * W_it (same W fragment)
                if (it > 0) {
                    f32x4 oc = {0.f, 0.f, 0.f, 0.f};
                    oc = __builtin_amdgcn_mfma_f32_16x16x32_bf16(aq0, w0, oc, 0, 0, 0);
                    oc = __builtin_amdgcn_mfma_f32_16x16x32_bf16(aq1, w1, oc, 0, 0, 0);
                    #pragma unroll
                    for (int j = 0; j < 4; ++j)
                        ob[((size_t)((it - 1) * MM) + r0 + (g << 2) + j) * (NH * ND) + (et << 4) + ln] = oc[j];
                }
            }
        }

        // issue xq(it+1), vq(it+1), qr(it): consumed after alpha+region2+beta
        if (it + 1 < NIT) {
            const float* xr = kb + (size_t)((it + 1) * MM + r0 + ln) * ND;
            xq[0] = *(const float4*)(xr + (g << 3));
            xq[1] = *(const float4*)(xr + (g << 3) + 4);
            xq[2] = *(const float4*)(xr + 32 + (g << 3));
            xq[3] = *(const float4*)(xr + 32 + (g << 3) + 4);
            const float* vp = vb + ((size_t)((it + 1) * MM) + r0 + (g << 2)) * ND + ln;
            #pragma unroll
            for (int et = 0; et < 4; ++et)
                #pragma unroll
                for (int j = 0; j < 4; ++j)
                    vq[et][j] = vp[(size_t)j * ND + (et << 4)];
        }
        {
            const float* qrow = qb + ((size_t)(it * MM) + r0 + ln) * ND;
            qr[0] = *(const float4*)(qrow + (g << 3));
            qr[1] = *(const float4*)(qrow + (g << 3) + 4);
            qr[2] = *(const float4*)(qrow + 32 + (g << 3));
            qr[3] = *(const float4*)(qrow + 32 + (g << 3) + 4);
        }

        barrier_lds();   // alpha: XT(it), ET(it) visible

        // ================= region 2: B(it) =================
        {
            f32x4 ga = {0.f, 0.f, 0.f, 0.f};
            #pragma unroll
            for (int kx = 0; kx < 8; ++kx) {
                bf16x8 af  = *(const bf16x8*)&XT[(d0 + ln) * T_P + (kx << 5) + (g << 3)];
                bf16x8 bf_ = *(const bf16x8*)&ET[(e0 + ln) * T_P + (kx << 5) + (g << 3)];
                ga = __builtin_amdgcn_mfma_f32_16x16x32_bf16(af, bf_, ga, 0, 0, 0);
            }
            ushort4 wq; unsigned short* wqp = (unsigned short*)&wq;
            #pragma unroll
            for (int j = 0; j < 4; ++j) {
                wf[j] -= scale * ga[j];
                wqp[j] = f2bf(wf[j]);
            }
            *(ushort4*)&WBT[(e0 + ln) * W_P + d0 + (g << 2)] = wq;
        }

        barrier_lds();   // beta: WBT(W_{it+1}) visible; XT free for overwrite
    }

    // ================= epilogue: C(NIT-1) with W_NIT =================
    {
        bf16x8 a0 = pack8(qr[0], qr[1]);
        bf16x8 a1 = pack8(qr[2], qr[3]);
        #pragma unroll
        for (int et = 0; et < 4; ++et) {
            bf16x8 w0 = *(const bf16x8*)&WBT[((et << 4) + ln) * W_P + (g << 3)];
            bf16x8 w1 = *(const bf16x8*)&WBT[((et << 4) + ln) * W_P + 32 + (g << 3)];
            f32x4 oc = {0.f, 0.f, 0.f, 0.f};
            oc = __builtin_amdgcn_mfma_f32_16x16x32_bf16(a0, w0, oc, 0, 0, 0);
            oc = __builtin_amdgcn_mfma_f32_16x16x32_bf16(a1, w1, oc, 0, 0, 0);
            #pragma unroll
            for (int j = 0; j < 4; ++j)
                ob[((size_t)((NIT - 1) * MM) + r0 + (g << 2) + j) * (NH * ND) + (et << 4) + ln] = oc[j];
        }
    }
}

extern "C" void kernel_launch(void* const* d_in, const int* in_sizes, int n_in,
                              void* d_out, int out_size, void* d_ws, size_t ws_size,
                              hipStream_t stream) {
    const float* q  = (const float*)d_in[0];
    const float* k  = (const float*)d_in[1];
    const float* v  = (const float*)d_in[2];
    const float* Wi = (const float*)d_in[3];
    float* out = (float*)d_out;

    int grid = in_sizes[0] / (NSEQ * ND);   // B * H = 192
    hipLaunchKernelGGL(ttt_fused, dim3(grid), dim3(1024), 0, stream,
                       q, k, v, Wi, out);
}